// Round 2
// baseline (470.665 us; speedup 1.0000x reference)
//
#include <hip/hip_runtime.h>
#include <stdint.h>

// WARP loss, B=1024, Y=50000. inputs: input_ f32[B*Y], target f32[B*Y],
// max_num_trials i32[1]; output f32[1] = sum of per-row losses.
//
// Exact-RNG reduction (absmax 0.0 verified): first violator in the random
// permutation == violator with min (u_bits>>9, col); num_trials-1 == rank ==
// #{cols != pos with key < kstar}.
// Keys are input-independent -> gen kernel pushes all keys with bits < 2^23
// (keyhi < 2^14) into per-row candidate lists (E~98/row) with NO input reads;
// finish kernel does margin tests only on candidates, falls back to an inline
// full wave-scan for rows with no violating candidate (P ~ 0.24^98 ~ never),
// and the last-finishing block reduces row_loss -> out[0] with EXACTLY the
// same summation order as the previous separate reduce_kernel.
#define BN 1024
#define YN 50000
#define SEGS 8              // threefry segments per row
#define SEGLEN 6250         // YN / SEGS
#define CAP 192             // per-row candidate capacity (Poisson(98), P(>192)~1e-17)

// ---------------- Threefry-2x32, key (0,42), counter (0, i) -----------------
#define TF_ROUND(r) { x0 += x1; x1 = (x1 << (r)) | (x1 >> (32 - (r))); x1 ^= x0; }

__device__ __forceinline__ uint32_t tf_bits(uint32_t ctr) {
    const uint32_t ks0 = 0u;
    const uint32_t ks1 = 42u;
    const uint32_t ks2 = 0x1BD11BDAu ^ 0u ^ 42u;
    uint32_t x1 = ctr + ks1;
    // round 1 specialized for x0 == 0 (c0 of the counter pair is always 0):
    uint32_t x0 = x1;
    x1 = ((x1 << 13) | (x1 >> 19)) ^ x0;
    TF_ROUND(15) TF_ROUND(26) TF_ROUND(6)
    x0 += ks1; x1 += ks2 + 1u;
    TF_ROUND(17) TF_ROUND(29) TF_ROUND(16) TF_ROUND(24)
    x0 += ks2; x1 += ks0 + 2u;
    TF_ROUND(13) TF_ROUND(15) TF_ROUND(26) TF_ROUND(6)
    x0 += ks0; x1 += ks1 + 3u;
    TF_ROUND(17) TF_ROUND(29) TF_ROUND(16) TF_ROUND(24)
    x0 += ks1; x1 += ks2 + 4u;
    TF_ROUND(13) TF_ROUND(15) TF_ROUND(26) TF_ROUND(6)
    x0 += ks2; x1 += ks0 + 5u;
    return x0 ^ x1;
}

// ws layout (4B units):
//   cnt[BN]      @ 0
//   done         @ BN          (last-block ticket; zeroed with cnt)
//   pos[BN]      @ 2*BN
//   ps[BN]       @ 3*BN
//   row_loss[BN] @ 4*BN
//   cand[BN*CAP] @ 5*BN
struct WS {
    uint32_t* cnt; uint32_t* done; int* pos; float* ps; float* row_loss; uint32_t* cand;
};
static inline WS ws_layout(void* d_ws) {
    uint32_t* p = (uint32_t*)d_ws;
    WS w;
    w.cnt = p; w.done = p + BN; w.pos = (int*)(p + 2 * BN);
    w.ps = (float*)(p + 3 * BN); w.row_loss = (float*)(p + 4 * BN);
    w.cand = p + 5 * BN;
    return w;
}

// ---------------- Kernel 1: candidate gen (threefry) + target scan ----------
// blocks [0, BN): target scan, one row each.
// blocks [BN, BN + BN*SEGS): threefry over one row segment each, unrolled x2.
__global__ __launch_bounds__(256) void gen_kernel(
    const float* __restrict__ input, const float* __restrict__ target,
    uint32_t* __restrict__ cnt, uint32_t* __restrict__ cand,
    int* __restrict__ pos_out, float* __restrict__ ps_out)
{
    const int tid = threadIdx.x;
    if (blockIdx.x < BN) {
        // ---- target scan role ----
        const int row = blockIdx.x;
        const size_t base = (size_t)row * YN;
        __shared__ volatile int s_pos;
        if (tid == 0) s_pos = -1;
        __syncthreads();
        const float4* t4 = (const float4*)(target + base);
        for (int j4 = tid; j4 < YN / 4; j4 += 256) {
            if (s_pos >= 0) break;               // benign racy early-exit
            float4 v = t4[j4];
            int c0 = 4 * j4;
            if (v.x != 0.0f) s_pos = c0;
            if (v.y != 0.0f) s_pos = c0 + 1;
            if (v.z != 0.0f) s_pos = c0 + 2;
            if (v.w != 0.0f) s_pos = c0 + 3;
        }
        __syncthreads();
        if (tid == 0) {
            int p = s_pos;
            pos_out[row] = p;
            ps_out[row] = input[base + p];
        }
        return;
    }
    // ---- threefry role (unrolled x2: two independent cipher chains) ----
    const int b = blockIdx.x - BN;
    const int row = b >> 3;                      // b / SEGS
    const int seg = b & 7;                       // b % SEGS
    const uint32_t base32 = (uint32_t)row * YN;
    const int start = seg * SEGLEN;
    const int end = start + SEGLEN;
    uint32_t* mycnt = cnt + row;
    uint32_t* mycand = cand + row * CAP;
    int col = start + tid;
    uint32_t ctr = base32 + (uint32_t)col;
    for (; col + 256 < end; col += 512, ctr += 512u) {
        uint32_t bits0 = tf_bits(ctr);
        uint32_t bits1 = tf_bits(ctr + 256u);
        if (bits0 < (1u << 23)) {
            uint32_t idx = atomicAdd(mycnt, 1u);
            if (idx < CAP) mycand[idx] = ((bits0 >> 9) << 17) | (uint32_t)col;
        }
        if (bits1 < (1u << 23)) {
            uint32_t idx = atomicAdd(mycnt, 1u);
            if (idx < CAP) mycand[idx] = ((bits1 >> 9) << 17) | (uint32_t)(col + 256);
        }
    }
    if (col < end) {
        uint32_t bits = tf_bits(ctr);
        if (bits < (1u << 23)) {
            uint32_t idx = atomicAdd(mycnt, 1u);
            if (idx < CAP) mycand[idx] = ((bits >> 9) << 17) | (uint32_t)col;
        }
    }
}

// ---------------- Kernel 2: resolve + inline fallback + last-block reduce ---
// one wave per row; grid = BN/4 blocks of 256.
__global__ __launch_bounds__(256) void finish_kernel(
    const float* __restrict__ input, const uint32_t* __restrict__ cnt,
    const uint32_t* __restrict__ cand, const int* __restrict__ pos_,
    const float* __restrict__ ps_, const int* __restrict__ mt_ptr,
    float* __restrict__ row_loss, uint32_t* __restrict__ done,
    float* __restrict__ out)
{
    const int tid = threadIdx.x;
    const int lane = tid & 63;
    const int row = blockIdx.x * 4 + (tid >> 6);
    const int pos = pos_[row];
    const float ps = ps_[row];
    const float* rowp = input + (size_t)row * YN;
    const uint32_t n = cnt[row];
    const uint32_t mt = (uint32_t)mt_ptr[0];
    float loss = 0.0f;
    bool need_fallback = (n > CAP);

    if (!need_fallback) {
        const uint32_t* cl = cand + row * CAP;
        // min packed key among violating candidates
        uint32_t mk = 0xFFFFFFFFu;
        for (uint32_t i = lane; i < n; i += 64) {
            uint32_t e = cl[i];
            int col = (int)(e & 0x1FFFFu);
            if (col != pos) {
                float s = rowp[col];
                if ((1.0f + s) - ps >= 0.0f) mk = (e < mk) ? e : mk;
            }
        }
        for (int off = 32; off > 0; off >>= 1) {
            uint32_t o = (uint32_t)__shfl_xor((int)mk, off, 64);
            mk = (o < mk) ? o : mk;
        }
        if (mk == 0xFFFFFFFFu) {
            need_fallback = true;   // no violating candidate (or truly none)
        } else {
            // rank = #{candidates: key < mk, col != pos}; all keys < kstar
            // are < T, hence in the list.
            uint32_t c = 0;
            for (uint32_t i = lane; i < n; i += 64) {
                uint32_t e = cl[i];
                int col = (int)(e & 0x1FFFFu);
                c += ((e < mk) && (col != pos)) ? 1u : 0u;
            }
            for (int off = 32; off > 0; off >>= 1)
                c += (uint32_t)__shfl_xor((int)c, off, 64);
            if (c < mt) {
                int cstar = (int)(mk & 0x1FFFFu);
                float ns = rowp[cstar];
                float nt = (float)(c + 1u);
                loss = logf(floorf(49999.0f / nt)) * ((1.0f - ps) + ns);
            }
        }
    }
    if (need_fallback) {
        // wave-level full scan (correctness path; essentially never taken)
        const uint32_t base32 = (uint32_t)row * YN;
        uint64_t mk = ~0ull;
        for (int col = lane; col < YN; col += 64) {
            uint32_t bits = tf_bits(base32 + (uint32_t)col);
            uint64_t key = ((uint64_t)(bits >> 9) << 17) | (uint32_t)col;
            float m = (1.0f + rowp[col]) - ps;
            if ((m >= 0.0f) && (col != pos) && (key < mk)) mk = key;
        }
        for (int off = 32; off > 0; off >>= 1) {
            uint64_t o = (uint64_t)__shfl_xor((long long)mk, off, 64);
            mk = (o < mk) ? o : mk;
        }
        if (mk != ~0ull) {
            uint32_t c = 0;
            for (int col = lane; col < YN; col += 64) {
                uint32_t bits = tf_bits(base32 + (uint32_t)col);
                uint64_t key = ((uint64_t)(bits >> 9) << 17) | (uint32_t)col;
                c += ((key < mk) && (col != pos)) ? 1u : 0u;
            }
            for (int off = 32; off > 0; off >>= 1)
                c += (uint32_t)__shfl_xor((int)c, off, 64);
            if (c < mt) {
                int cstar = (int)(mk & 0x1FFFFull);
                float ns = rowp[cstar];
                float nt = (float)(c + 1u);
                loss = logf(floorf(49999.0f / nt)) * ((1.0f - ps) + ns);
            }
        }
    }
    if (lane == 0) row_loss[row] = loss;

    // ---- last-block reduction (exact same order as old reduce_kernel) ----
    __threadfence();            // release row_loss
    __syncthreads();
    __shared__ bool s_last;
    if (tid == 0) s_last = (atomicAdd(done, 1u) == (uint32_t)(gridDim.x - 1));
    __syncthreads();
    if (s_last) {
        __threadfence();        // acquire row_loss from other blocks/XCDs
        __shared__ float s[256];
        float acc = 0.0f;
        for (int i = tid; i < BN; i += 256) acc += row_loss[i];
        s[tid] = acc;
        __syncthreads();
        for (int st = 128; st > 0; st >>= 1) {
            if (tid < st) s[tid] += s[tid + st];
            __syncthreads();
        }
        if (tid == 0) out[0] = s[0];
    }
}

extern "C" void kernel_launch(void* const* d_in, const int* in_sizes, int n_in,
                              void* d_out, int out_size, void* d_ws, size_t ws_size,
                              hipStream_t stream) {
    const float* input  = (const float*)d_in[0];
    const float* target = (const float*)d_in[1];
    const int*   mt     = (const int*)d_in[2];
    float* out = (float*)d_out;
    WS w = ws_layout(d_ws);

    // zero cnt + done (harness poisons ws with 0xAA before every launch)
    hipMemsetAsync(d_ws, 0, 2 * BN * sizeof(uint32_t), stream);

    gen_kernel<<<BN + BN * SEGS, 256, 0, stream>>>(
        input, target, w.cnt, w.cand, w.pos, w.ps);
    finish_kernel<<<BN / 4, 256, 0, stream>>>(
        input, w.cnt, w.cand, w.pos, w.ps, mt, w.row_loss, w.done, out);
}